// Round 18
// baseline (63.456 us; speedup 1.0000x reference)
//
#include <hip/hip_runtime.h>
#include <stdint.h>

typedef int i32x4 __attribute__((ext_vector_type(4)));

// xpad layout (i8): [n][row 0..57][cs8 0..7][col 0..57][16c]  (16B chunk = 16 ch)
// wq   layout (i8): [kk 0..8][cs8 0..7][o 0..255][16c]
// Scales: w_i8 = 4*w (exact); x_i8 = round(x*127/6); out = i32acc * 1.5/127.
#define XPAD_I8_BYTES ((size_t)32 * 58 * 58 * 8 * 16)
#define OUT_SCALE (1.5f / 127.0f)

static __device__ __forceinline__ i32x4 ldfrag(const signed char* p) {
    return *(const i32x4*)p;
}

static __device__ __forceinline__ void gload16(const signed char* g, signed char* l) {
    __builtin_amdgcn_global_load_lds(
        (const __attribute__((address_space(1))) uint32_t*)g,
        (__attribute__((address_space(3))) uint32_t*)l, 16, 0, 0);
}

// ---------------- fused pre-pass: border zero + quant + x transform ----------------
__global__ __launch_bounds__(256) void pre_k(const float* __restrict__ pc,
                                             const float* __restrict__ ql,
                                             const float* __restrict__ x,
                                             signed char* __restrict__ wq,
                                             signed char* __restrict__ xpad) {
    int b = blockIdx.x;
    int tid = threadIdx.x;
    if (b < 228) {
        int i = b * 256 + tid;
        if (i < 58368) {
            int n = i / 1824;
            int rem = i - n * 1824;
            int r, cs, col;
            if (rem < 928) {
                int rt = rem / 464;
                int q = rem - rt * 464;
                r = rt * 57;
                cs = q / 58;
                col = q - cs * 58;
            } else {
                int rem2 = rem - 928;
                int ct = rem2 / 448;
                int q = rem2 - ct * 448;
                col = ct * 57;
                cs = q / 56;
                r = 1 + (q - cs * 56);
            }
            const i32x4 z = (i32x4){0, 0, 0, 0};
            *(i32x4*)(xpad + ((((size_t)n * 58 + r) * 8 + cs) * 58 + col) * 16) = z;
        }
    } else if (b < 1380) {
        int p = (b - 228) * 256 + tid;
        int j = p & 15;
        int o = (p >> 4) & 255;
        int cs = (p >> 12) & 7;
        int kk = p >> 15;
        int c = cs * 16 + j;
        const float* v = pc + ((size_t)((o * 128 + c) * 9 + kk) * 7);
        float vv[7];
        float s = 0.f;
#pragma unroll
        for (int l = 0; l < 7; ++l) { vv[l] = v[l]; s += vv[l] * vv[l]; }
        float norm = sqrtf(s);
        float best = 10.0f * (vv[0] / norm);
        int bi = 0;
#pragma unroll
        for (int l = 1; l < 7; ++l) {
            float t = 10.0f * (vv[l] / norm);
            if (t > best) { best = t; bi = l; }
        }
        wq[p] = (signed char)__float2int_rn(ql[bi] * 4.0f);
    } else {
        int b2 = b - 1380;            // 0..1791 = 32 n x 56 h
        int n = b2 / 56;
        int h = b2 - n * 56;
#pragma unroll
        for (int it = 0; it < 2; ++it) {
            int idx = it * 256 + tid;     // 0..447 = 8 cs x 56 col
            if (idx < 448) {
                int cs = idx / 56;
                int col = idx - cs * 56;
                const float* src = x + ((size_t)(n * 128 + cs * 16) * 56 + h) * 56 + col;
                signed char d[16];
#pragma unroll
                for (int jj = 0; jj < 16; ++jj) {
                    float vf = src[(size_t)jj * 3136] * (127.0f / 6.0f);
                    vf = fminf(fmaxf(vf, -127.0f), 127.0f);
                    d[jj] = (signed char)__float2int_rn(vf);
                }
                *(i32x4*)(xpad + ((((size_t)n * 58 + h + 1) * 8 + cs) * 58 + (col + 1)) * 16)
                    = *(const i32x4*)d;
            }
        }
    }
}

// ---------------- implicit-GEMM conv v16: conv13 (proven 54.0 µs) + nt stores ----------------
// Byte-identical structure to r15's conv13: 64o x (4 rows x 56), 128 thr = 2
// waves, i8 K=64 MFMA, T5 setprio, T1 XCD swizzle, A global->reg 1-deep
// prefetch, xs single-buffer 22528 B, 7 blocks/CU.
// ONLY change: epilogue stores are non-temporal (no L2 write-allocate) so the
// 100 MB output stream stops evicting the xpad/wq working set.
__global__ __launch_bounds__(128, 2) void conv16_k(const signed char* __restrict__ xpad,
                                                   const signed char* __restrict__ wq,
                                                   float* __restrict__ out) {
    __shared__ __align__(16) signed char xs[4 * 352 * 16];   // 22528 B

    const int tid = threadIdx.x;
    // ---- XCD-aware swizzle (bijective: 1792 % 8 == 0) ----
    const int wg = blockIdx.x;
    const int idx = (wg & 7) * 224 + (wg >> 3);
    const int n = idx / 56;
    const int r2 = idx - n * 56;
    const int h0 = (r2 >> 2) * 4;
    const int o0 = (r2 & 3) * 64;

    const int lane = tid & 63;
    const int wave = tid >> 6;
    const int l16 = lane & 15;
    const int kgrp = lane >> 4;

    // ---- x staging source byte-offsets: 1408 chunks (4 cs8 x 352, 348 used) ----
    int offx[11];
#pragma unroll
    for (int i = 0; i < 11; ++i) {
        int ci = i * 128 + tid;
        int cs = ci / 352;
        int pos = ci - cs * 352;
        int pe = pos < 348 ? pos : 347;
        int r = pe / 58;
        int col = pe - r * 58;
        offx[i] = ((((n * 58 + h0 + r) * 8) + cs) * 58 + col) * 16;
    }

    // ---- B-fragment LDS byte-bases ----
    int bb[7];
#pragma unroll
    for (int f = 0; f < 7; ++f) {
        int s = wave * 112 + f * 16 + l16;
        int r = s / 56;
        int w = s - r * 56;
        bb[f] = (kgrp * 352 + r * 58 + w) * 16;
    }

    // ---- A-fragment global base: A(kk,t,of) = wA + kk*32768 + t*16384 + of*256 B ----
    const signed char* wA = wq + (size_t)kgrp * 4096 + (size_t)(o0 + l16) * 16;

    i32x4 acc[4][7];
#pragma unroll
    for (int a = 0; a < 4; ++a)
#pragma unroll
        for (int f = 0; f < 7; ++f) acc[a][f] = (i32x4){0, 0, 0, 0};

    // ---- prologue: stage chunk 0 (channels 0..63) ----
#pragma unroll
    for (int i = 0; i < 11; ++i)
        gload16(xpad + offx[i], &xs[(i * 128 + wave * 64) * 16]);
    __syncthreads();

#pragma unroll
    for (int t = 0; t < 2; ++t) {
        i32x4 A0[4], A1[4];
#pragma unroll
        for (int of = 0; of < 4; ++of)
            A0[of] = ldfrag(wA + t * 16384 + of * 256);

#pragma unroll
        for (int kk = 0; kk < 9; ++kk) {
            i32x4 Ac[4];
#pragma unroll
            for (int of = 0; of < 4; ++of) Ac[of] = (kk & 1) ? A1[of] : A0[of];
            if (kk < 8) {
#pragma unroll
                for (int of = 0; of < 4; ++of) {
                    i32x4 vld = ldfrag(wA + (kk + 1) * 32768 + t * 16384 + of * 256);
                    if (kk & 1) A0[of] = vld; else A1[of] = vld;
                }
            }
            const int kh = kk / 3;
            const int kw = kk - kh * 3;
            const int xo = (kh * 58 + kw) * 16;

            __builtin_amdgcn_s_setprio(1);
#pragma unroll
            for (int f = 0; f < 7; ++f) {
                i32x4 bfrag = ldfrag(&xs[bb[f] + xo]);
                acc[0][f] = __builtin_amdgcn_mfma_i32_16x16x64_i8(Ac[0], bfrag, acc[0][f], 0, 0, 0);
                acc[1][f] = __builtin_amdgcn_mfma_i32_16x16x64_i8(Ac[1], bfrag, acc[1][f], 0, 0, 0);
                acc[2][f] = __builtin_amdgcn_mfma_i32_16x16x64_i8(Ac[2], bfrag, acc[2][f], 0, 0, 0);
                acc[3][f] = __builtin_amdgcn_mfma_i32_16x16x64_i8(Ac[3], bfrag, acc[3][f], 0, 0, 0);
            }
            __builtin_amdgcn_s_setprio(0);
        }

        if (t < 1) {
            __syncthreads();
#pragma unroll
            for (int i = 0; i < 11; ++i)
                gload16(xpad + offx[i] + 3712, &xs[(i * 128 + wave * 64) * 16]);
            __syncthreads();
        }
    }

    // ---- epilogue: i32 -> f32 scale, NON-TEMPORAL stores (no L2 write-allocate) ----
#pragma unroll
    for (int of = 0; of < 4; ++of) {
        int ob = o0 + of * 16 + kgrp * 4;
#pragma unroll
        for (int f = 0; f < 7; ++f) {
            int s = wave * 112 + f * 16 + l16;
            int r = s / 56;
            int w = s - r * 56;
            int h = h0 + r;
            float* dst = out + ((size_t)(n * 256 + ob) * 56 + h) * 56 + w;
#pragma unroll
            for (int j = 0; j < 4; ++j)
                __builtin_nontemporal_store((float)acc[of][f][j] * OUT_SCALE,
                                            dst + (size_t)j * 3136);
        }
    }
}

extern "C" void kernel_launch(void* const* d_in, const int* in_sizes, int n_in,
                              void* d_out, int out_size, void* d_ws, size_t ws_size,
                              hipStream_t stream) {
    const float* x = (const float*)d_in[0];
    const float* pc = (const float*)d_in[1];
    const float* ql = (const float*)d_in[2];
    float* out = (float*)d_out;

    signed char* xpad = (signed char*)d_ws;
    signed char* wq = (signed char*)d_ws + XPAD_I8_BYTES;

    pre_k<<<3172, 256, 0, stream>>>(pc, ql, x, wq, xpad);
    conv16_k<<<1792, 128, 0, stream>>>(xpad, wq, out);
}

// Round 19
// 54.092 us; speedup vs baseline: 1.1731x; 1.1731x over previous
//
#include <hip/hip_runtime.h>
#include <stdint.h>

typedef int i32x4 __attribute__((ext_vector_type(4)));

// xpad layout (i8): [n][row 0..57][cs8 0..7][col 0..57][16c]  (16B chunk = 16 ch)
// wq   layout (i8): [kk 0..8][cs8 0..7][o 0..255][16c]
// Scales: w_i8 = 4*w (exact); x_i8 = round(x*127/6); out = i32acc * 1.5/127.
#define XPAD_I8_BYTES ((size_t)32 * 58 * 58 * 8 * 16)
#define OUT_SCALE (1.5f / 127.0f)

static __device__ __forceinline__ i32x4 ldfrag(const signed char* p) {
    return *(const i32x4*)p;
}

static __device__ __forceinline__ void gload16(const signed char* g, signed char* l) {
    __builtin_amdgcn_global_load_lds(
        (const __attribute__((address_space(1))) uint32_t*)g,
        (__attribute__((address_space(3))) uint32_t*)l, 16, 0, 0);
}

// ---------------- fused pre-pass: border zero + quant + x transform ----------------
__global__ __launch_bounds__(256) void pre_k(const float* __restrict__ pc,
                                             const float* __restrict__ ql,
                                             const float* __restrict__ x,
                                             signed char* __restrict__ wq,
                                             signed char* __restrict__ xpad) {
    int b = blockIdx.x;
    int tid = threadIdx.x;
    if (b < 228) {
        int i = b * 256 + tid;
        if (i < 58368) {
            int n = i / 1824;
            int rem = i - n * 1824;
            int r, cs, col;
            if (rem < 928) {
                int rt = rem / 464;
                int q = rem - rt * 464;
                r = rt * 57;
                cs = q / 58;
                col = q - cs * 58;
            } else {
                int rem2 = rem - 928;
                int ct = rem2 / 448;
                int q = rem2 - ct * 448;
                col = ct * 57;
                cs = q / 56;
                r = 1 + (q - cs * 56);
            }
            const i32x4 z = (i32x4){0, 0, 0, 0};
            *(i32x4*)(xpad + ((((size_t)n * 58 + r) * 8 + cs) * 58 + col) * 16) = z;
        }
    } else if (b < 1380) {
        int p = (b - 228) * 256 + tid;
        int j = p & 15;
        int o = (p >> 4) & 255;
        int cs = (p >> 12) & 7;
        int kk = p >> 15;
        int c = cs * 16 + j;
        const float* v = pc + ((size_t)((o * 128 + c) * 9 + kk) * 7);
        float vv[7];
        float s = 0.f;
#pragma unroll
        for (int l = 0; l < 7; ++l) { vv[l] = v[l]; s += vv[l] * vv[l]; }
        float norm = sqrtf(s);
        float best = 10.0f * (vv[0] / norm);
        int bi = 0;
#pragma unroll
        for (int l = 1; l < 7; ++l) {
            float t = 10.0f * (vv[l] / norm);
            if (t > best) { best = t; bi = l; }
        }
        wq[p] = (signed char)__float2int_rn(ql[bi] * 4.0f);
    } else {
        int b2 = b - 1380;            // 0..1791 = 32 n x 56 h
        int n = b2 / 56;
        int h = b2 - n * 56;
#pragma unroll
        for (int it = 0; it < 2; ++it) {
            int idx = it * 256 + tid;     // 0..447 = 8 cs x 56 col
            if (idx < 448) {
                int cs = idx / 56;
                int col = idx - cs * 56;
                const float* src = x + ((size_t)(n * 128 + cs * 16) * 56 + h) * 56 + col;
                signed char d[16];
#pragma unroll
                for (int jj = 0; jj < 16; ++jj) {
                    float vf = src[(size_t)jj * 3136] * (127.0f / 6.0f);
                    vf = fminf(fmaxf(vf, -127.0f), 127.0f);
                    d[jj] = (signed char)__float2int_rn(vf);
                }
                *(i32x4*)(xpad + ((((size_t)n * 58 + h + 1) * 8 + cs) * 58 + (col + 1)) * 16)
                    = *(const i32x4*)d;
            }
        }
    }
}

// ---------------- implicit-GEMM conv v13 (RESTORED — proven 54.0 µs, r15) ----------------
// 64o x (4 rows x 56), 128 thr = 2 waves; i8 K=64 MFMA; T5 setprio; T1 XCD
// swizzle; A global->reg 1-deep prefetch; xs single-buffer 22528 B, 7 blk/CU.
// r16-r18 post-mortems: dbuf (-7%), f-split (-4%), nt stores (-17%) all
// regressed -> this schedule is the measured optimum of the structure.
__global__ __launch_bounds__(128, 2) void conv13_k(const signed char* __restrict__ xpad,
                                                   const signed char* __restrict__ wq,
                                                   float* __restrict__ out) {
    __shared__ __align__(16) signed char xs[4 * 352 * 16];   // 22528 B

    const int tid = threadIdx.x;
    // ---- XCD-aware swizzle (bijective: 1792 % 8 == 0) ----
    const int wg = blockIdx.x;
    const int idx = (wg & 7) * 224 + (wg >> 3);
    const int n = idx / 56;
    const int r2 = idx - n * 56;
    const int h0 = (r2 >> 2) * 4;
    const int o0 = (r2 & 3) * 64;

    const int lane = tid & 63;
    const int wave = tid >> 6;
    const int l16 = lane & 15;
    const int kgrp = lane >> 4;

    // ---- x staging source byte-offsets: 1408 chunks (4 cs8 x 352, 348 used) ----
    int offx[11];
#pragma unroll
    for (int i = 0; i < 11; ++i) {
        int ci = i * 128 + tid;
        int cs = ci / 352;
        int pos = ci - cs * 352;
        int pe = pos < 348 ? pos : 347;
        int r = pe / 58;
        int col = pe - r * 58;
        offx[i] = ((((n * 58 + h0 + r) * 8) + cs) * 58 + col) * 16;
    }

    // ---- B-fragment LDS byte-bases ----
    int bb[7];
#pragma unroll
    for (int f = 0; f < 7; ++f) {
        int s = wave * 112 + f * 16 + l16;
        int r = s / 56;
        int w = s - r * 56;
        bb[f] = (kgrp * 352 + r * 58 + w) * 16;
    }

    // ---- A-fragment global base: A(kk,t,of) = wA + kk*32768 + t*16384 + of*256 B ----
    const signed char* wA = wq + (size_t)kgrp * 4096 + (size_t)(o0 + l16) * 16;

    i32x4 acc[4][7];
#pragma unroll
    for (int a = 0; a < 4; ++a)
#pragma unroll
        for (int f = 0; f < 7; ++f) acc[a][f] = (i32x4){0, 0, 0, 0};

    // ---- prologue: stage chunk 0 (channels 0..63) ----
#pragma unroll
    for (int i = 0; i < 11; ++i)
        gload16(xpad + offx[i], &xs[(i * 128 + wave * 64) * 16]);
    __syncthreads();

#pragma unroll
    for (int t = 0; t < 2; ++t) {
        i32x4 A0[4], A1[4];
#pragma unroll
        for (int of = 0; of < 4; ++of)
            A0[of] = ldfrag(wA + t * 16384 + of * 256);

#pragma unroll
        for (int kk = 0; kk < 9; ++kk) {
            i32x4 Ac[4];
#pragma unroll
            for (int of = 0; of < 4; ++of) Ac[of] = (kk & 1) ? A1[of] : A0[of];
            if (kk < 8) {
#pragma unroll
                for (int of = 0; of < 4; ++of) {
                    i32x4 vld = ldfrag(wA + (kk + 1) * 32768 + t * 16384 + of * 256);
                    if (kk & 1) A0[of] = vld; else A1[of] = vld;
                }
            }
            const int kh = kk / 3;
            const int kw = kk - kh * 3;
            const int xo = (kh * 58 + kw) * 16;

            __builtin_amdgcn_s_setprio(1);
#pragma unroll
            for (int f = 0; f < 7; ++f) {
                i32x4 bfrag = ldfrag(&xs[bb[f] + xo]);
                acc[0][f] = __builtin_amdgcn_mfma_i32_16x16x64_i8(Ac[0], bfrag, acc[0][f], 0, 0, 0);
                acc[1][f] = __builtin_amdgcn_mfma_i32_16x16x64_i8(Ac[1], bfrag, acc[1][f], 0, 0, 0);
                acc[2][f] = __builtin_amdgcn_mfma_i32_16x16x64_i8(Ac[2], bfrag, acc[2][f], 0, 0, 0);
                acc[3][f] = __builtin_amdgcn_mfma_i32_16x16x64_i8(Ac[3], bfrag, acc[3][f], 0, 0, 0);
            }
            __builtin_amdgcn_s_setprio(0);
        }

        if (t < 1) {
            __syncthreads();
#pragma unroll
            for (int i = 0; i < 11; ++i)
                gload16(xpad + offx[i] + 3712, &xs[(i * 128 + wave * 64) * 16]);
            __syncthreads();
        }
    }

    // ---- epilogue: i32 -> f32 scale; C/D mapping verified rounds 1-18 ----
#pragma unroll
    for (int of = 0; of < 4; ++of) {
        int ob = o0 + of * 16 + kgrp * 4;
#pragma unroll
        for (int f = 0; f < 7; ++f) {
            int s = wave * 112 + f * 16 + l16;
            int r = s / 56;
            int w = s - r * 56;
            int h = h0 + r;
            float* dst = out + ((size_t)(n * 256 + ob) * 56 + h) * 56 + w;
#pragma unroll
            for (int j = 0; j < 4; ++j)
                dst[(size_t)j * 3136] = (float)acc[of][f][j] * OUT_SCALE;
        }
    }
}

extern "C" void kernel_launch(void* const* d_in, const int* in_sizes, int n_in,
                              void* d_out, int out_size, void* d_ws, size_t ws_size,
                              hipStream_t stream) {
    const float* x = (const float*)d_in[0];
    const float* pc = (const float*)d_in[1];
    const float* ql = (const float*)d_in[2];
    float* out = (float*)d_out;

    signed char* xpad = (signed char*)d_ws;
    signed char* wq = (signed char*)d_ws + XPAD_I8_BYTES;

    pre_k<<<3172, 256, 0, stream>>>(pc, ql, x, wq, xpad);
    conv13_k<<<1792, 128, 0, stream>>>(xpad, wq, out);
}